// Round 1
// baseline (1662.129 us; speedup 1.0000x reference)
//
#include <hip/hip_runtime.h>

#define N_NODES 50000
#define N_EDGES 1600000
#define IN_DIM  128
#define D       64      // OUT_DIM
#define E_IN    32
#define E_OUT   32

// ---------------------------------------------------------------------------
// K1: per-node precompute.  z = h @ W_node  [N,64]
//     s1 = z @ W_attn[:64], s2 = z @ W_attn[64:128]   (attention halves)
//     u  = z @ W_tonode[:64]                           [N,64]
// One wave per node, lane j owns output column j. Weights staged in LDS.
// ---------------------------------------------------------------------------
__global__ __launch_bounds__(256) void node_a_kernel(
    const float* __restrict__ h, const float* __restrict__ Wn,
    const float* __restrict__ Wa, const float* __restrict__ Wt,
    float* __restrict__ z, float* __restrict__ u,
    float* __restrict__ s1, float* __restrict__ s2)
{
    __shared__ float lWn[IN_DIM * D];   // 32 KB
    __shared__ float lWt1[D * D];       // 16 KB
    __shared__ float lWa[2 * D];        // 512 B
    __shared__ float lh[4][IN_DIM];     // per-wave h-row staging
    __shared__ float lz[4][D];          // per-wave z-row staging

    const int tid = threadIdx.x;
    for (int i = tid; i < IN_DIM * D; i += 256) lWn[i] = Wn[i];
    for (int i = tid; i < D * D; i += 256) lWt1[i] = Wt[i];
    if (tid < 2 * D) lWa[tid] = Wa[tid];
    __syncthreads();

    const int wid = tid >> 6;
    const int lane = tid & 63;
    const int nwaves = gridDim.x * 4;

    for (int n = blockIdx.x * 4 + wid; n < N_NODES; n += nwaves) {
        // stage h row (wave-private LDS region; same-wave RAW is ordered)
        lh[wid][lane]      = h[(size_t)n * IN_DIM + lane];
        lh[wid][lane + 64] = h[(size_t)n * IN_DIM + 64 + lane];

        float acc = 0.f;
        #pragma unroll 8
        for (int k = 0; k < IN_DIM; ++k)
            acc = fmaf(lh[wid][k], lWn[k * D + lane], acc);
        z[(size_t)n * D + lane] = acc;
        lz[wid][lane] = acc;

        float p1 = acc * lWa[lane];
        float p2 = acc * lWa[D + lane];
        #pragma unroll
        for (int off = 32; off > 0; off >>= 1) {
            p1 += __shfl_xor(p1, off, 64);
            p2 += __shfl_xor(p2, off, 64);
        }
        if (lane == 0) { s1[n] = p1; s2[n] = p2; }

        float ua = 0.f;
        #pragma unroll 8
        for (int k = 0; k < D; ++k)
            ua = fmaf(lz[wid][k], lWt1[k * D + lane], ua);
        u[(size_t)n * D + lane] = ua;
    }
}

// ---------------------------------------------------------------------------
// K2: edge pass A. One wave per edge (edge index wave-uniform so edge_w /
// src / dst / s1 / s2 loads can be scalarized).
//   a  = s1[src] + s2[dst] + ew @ Wa[128:]
//   ex = exp(leaky_relu(a, 0.1))            (no max-subtraction needed:
//                                            logits bounded ~N(0,1))
//   t  = u[src] + ew @ W_tonode[64:]
//   h_raw[dst] += ex * t ; denom[dst] += ex   (atomics)
// ---------------------------------------------------------------------------
__global__ __launch_bounds__(256) void edge_a_kernel(
    const float* __restrict__ edge_w, const int* __restrict__ src,
    const int* __restrict__ dst, const float* __restrict__ Wa,
    const float* __restrict__ Wt, const float* __restrict__ u,
    const float* __restrict__ s1, const float* __restrict__ s2,
    float* __restrict__ hraw, float* __restrict__ denom)
{
    const int lane = threadIdx.x & 63;
    const int wid = __builtin_amdgcn_readfirstlane(threadIdx.x >> 6);
    const int gwid = blockIdx.x * 4 + wid;
    const int nw = gridDim.x * 4;

    // lane j holds W_tonode[64+k][j]; attention weights lane-invariant
    float wt2r[E_IN], war[E_IN];
    #pragma unroll
    for (int k = 0; k < E_IN; ++k) {
        wt2r[k] = Wt[(D + k) * D + lane];
        war[k]  = Wa[2 * D + k];
    }

    for (int e = gwid; e < N_EDGES; e += nw) {
        const int s = src[e];
        const int d = dst[e];
        const float base = s1[s] + s2[d];

        const float4* ew4 = (const float4*)(edge_w + (size_t)e * E_IN);
        float ew[E_IN];
        #pragma unroll
        for (int qq = 0; qq < E_IN / 4; ++qq) {
            float4 v = ew4[qq];
            ew[4*qq+0] = v.x; ew[4*qq+1] = v.y;
            ew[4*qq+2] = v.z; ew[4*qq+3] = v.w;
        }

        float a = base;
        float t = u[(size_t)s * D + lane];
        #pragma unroll
        for (int k = 0; k < E_IN; ++k) {
            a = fmaf(ew[k], war[k], a);
            t = fmaf(ew[k], wt2r[k], t);
        }

        float lr = (a > 0.f) ? a : 0.1f * a;
        float ex = __expf(lr);

        atomicAdd(hraw + (size_t)d * D + lane, ex * t);
        if (lane == 0) atomicAdd(denom + d, ex);
    }
}

// ---------------------------------------------------------------------------
// K3: per-node finalize + precompute for edge pass B.
//   h_new = denom>0 ? h_raw/denom : z      -> d_out[0 : N*64]
//   p = h_new @ W_edge[:64]    [N,32]
//   q = h_new @ W_edge[64:128] [N,32]
// lanes 0..31 compute p, lanes 32..63 compute q (interleaved weight tile).
// ---------------------------------------------------------------------------
__global__ __launch_bounds__(256) void node_b_kernel(
    const float* __restrict__ hraw, const float* __restrict__ denom,
    const float* __restrict__ z, const float* __restrict__ We,
    float* __restrict__ hout, float* __restrict__ p, float* __restrict__ q)
{
    __shared__ float lWE[D * 64];   // 16 KB: [j][l] l<32 -> We1[j][l], else We2[j][l-32]
    __shared__ float lh[4][D];
    const int tid = threadIdx.x;
    for (int i = tid; i < D * 64; i += 256) {
        int j = i >> 6, l = i & 63;
        lWE[i] = We[(j + ((l < 32) ? 0 : D)) * E_OUT + (l & 31)];
    }
    __syncthreads();

    const int wid = tid >> 6, lane = tid & 63;
    const int nwaves = gridDim.x * 4;
    for (int n = blockIdx.x * 4 + wid; n < N_NODES; n += nwaves) {
        const float dn = denom[n];
        float hv;
        if (dn > 0.f) hv = hraw[(size_t)n * D + lane] / dn;
        else          hv = z[(size_t)n * D + lane];
        hout[(size_t)n * D + lane] = hv;
        lh[wid][lane] = hv;

        float acc = 0.f;
        #pragma unroll 8
        for (int j = 0; j < D; ++j)
            acc = fmaf(lh[wid][j], lWE[j * 64 + lane], acc);

        float* o = (lane < 32) ? p : q;
        o[(size_t)n * E_OUT + (lane & 31)] = acc;
    }
}

// ---------------------------------------------------------------------------
// K4: edge pass B. Two consecutive edges per wave (lane>>5 selects edge),
// lane&31 owns an output column. w = p[src] + q[dst] + ew @ W_edge[128:].
// Store is a fully-coalesced 256B per wave (two contiguous edge rows).
// ---------------------------------------------------------------------------
__global__ __launch_bounds__(256) void edge_b_kernel(
    const float* __restrict__ edge_w, const int* __restrict__ src,
    const int* __restrict__ dst, const float* __restrict__ We,
    const float* __restrict__ p, const float* __restrict__ q,
    float* __restrict__ wout)
{
    const int lane = threadIdx.x & 63;
    const int i = lane & 31;
    const int half = lane >> 5;
    const int wp0 = blockIdx.x * 4 + (threadIdx.x >> 6);
    const int npairs = N_EDGES / 2;
    const int nw = gridDim.x * 4;

    float we3r[E_IN];
    #pragma unroll
    for (int k = 0; k < E_IN; ++k) we3r[k] = We[(2 * D + k) * E_OUT + i];

    for (int wp = wp0; wp < npairs; wp += nw) {
        const int e = 2 * wp + half;
        const int s = src[e], d = dst[e];
        float acc = p[(size_t)s * E_OUT + i] + q[(size_t)d * E_OUT + i];
        const float4* ew4 = (const float4*)(edge_w + (size_t)e * E_IN);
        #pragma unroll
        for (int qq = 0; qq < E_IN / 4; ++qq) {
            float4 v = ew4[qq];
            acc = fmaf(v.x, we3r[4*qq+0], acc);
            acc = fmaf(v.y, we3r[4*qq+1], acc);
            acc = fmaf(v.z, we3r[4*qq+2], acc);
            acc = fmaf(v.w, we3r[4*qq+3], acc);
        }
        wout[(size_t)e * E_OUT + i] = acc;
    }
}

// ---------------------------------------------------------------------------
extern "C" void kernel_launch(void* const* d_in, const int* in_sizes, int n_in,
                              void* d_out, int out_size, void* d_ws, size_t ws_size,
                              hipStream_t stream) {
    const float* h  = (const float*)d_in[0];
    const float* ew = (const float*)d_in[1];
    const float* Wn = (const float*)d_in[2];
    const float* Wa = (const float*)d_in[3];
    const float* Wt = (const float*)d_in[4];
    const float* We = (const float*)d_in[5];
    const int* src  = (const int*)d_in[6];
    const int* dst  = (const int*)d_in[7];

    float* z     = (float*)d_ws;                    // N*64
    float* u     = z + (size_t)N_NODES * D;         // N*64 (reused as p/q later)
    float* hraw  = u + (size_t)N_NODES * D;         // N*64 (memset 0)
    float* denom = hraw + (size_t)N_NODES * D;      // N    (memset 0, contiguous w/ hraw)
    float* s1    = denom + N_NODES;                 // N
    float* s2    = s1 + N_NODES;                    // N
    float* p     = u;                               // u is dead after edge_a
    float* q     = u + (size_t)N_NODES * E_OUT;

    float* hout = (float*)d_out;
    float* wout = hout + (size_t)N_NODES * D;

    hipMemsetAsync(hraw, 0, ((size_t)N_NODES * D + N_NODES) * sizeof(float), stream);

    node_a_kernel<<<1024, 256, 0, stream>>>(h, Wn, Wa, Wt, z, u, s1, s2);
    edge_a_kernel<<<2048, 256, 0, stream>>>(ew, src, dst, Wa, Wt, u, s1, s2, hraw, denom);
    node_b_kernel<<<1024, 256, 0, stream>>>(hraw, denom, z, We, hout, p, q);
    edge_b_kernel<<<2048, 256, 0, stream>>>(ew, src, dst, We, p, q, wout);
}

// Round 2
// 1401.601 us; speedup vs baseline: 1.1859x; 1.1859x over previous
//
#include <hip/hip_runtime.h>

#define N_NODES 50000
#define N_EDGES 1600000
#define IN_DIM  128
#define D       64      // OUT_DIM
#define E_IN    32
#define E_OUT   32
#define SCAN_CHUNK 256
#define N_CHUNKS ((N_NODES + SCAN_CHUNK - 1) / SCAN_CHUNK)   // 196

// ---------------------------------------------------------------------------
// K1: per-node precompute.  z = h @ W_node  [N,64]
//     s1 = z @ W_attn[:64], s2 = z @ W_attn[64:128]
//     u  = z @ W_tonode[:64]                [N,64]
// ---------------------------------------------------------------------------
__global__ __launch_bounds__(256) void node_a_kernel(
    const float* __restrict__ h, const float* __restrict__ Wn,
    const float* __restrict__ Wa, const float* __restrict__ Wt,
    float* __restrict__ z, float* __restrict__ u,
    float* __restrict__ s1, float* __restrict__ s2)
{
    __shared__ float lWn[IN_DIM * D];   // 32 KB
    __shared__ float lWt1[D * D];       // 16 KB
    __shared__ float lWa[2 * D];
    __shared__ float lh[4][IN_DIM];
    __shared__ float lz[4][D];

    const int tid = threadIdx.x;
    for (int i = tid; i < IN_DIM * D; i += 256) lWn[i] = Wn[i];
    for (int i = tid; i < D * D; i += 256) lWt1[i] = Wt[i];
    if (tid < 2 * D) lWa[tid] = Wa[tid];
    __syncthreads();

    const int wid = tid >> 6;
    const int lane = tid & 63;
    const int nwaves = gridDim.x * 4;

    for (int n = blockIdx.x * 4 + wid; n < N_NODES; n += nwaves) {
        lh[wid][lane]      = h[(size_t)n * IN_DIM + lane];
        lh[wid][lane + 64] = h[(size_t)n * IN_DIM + 64 + lane];

        float acc = 0.f;
        #pragma unroll 8
        for (int k = 0; k < IN_DIM; ++k)
            acc = fmaf(lh[wid][k], lWn[k * D + lane], acc);
        z[(size_t)n * D + lane] = acc;
        lz[wid][lane] = acc;

        float p1 = acc * lWa[lane];
        float p2 = acc * lWa[D + lane];
        #pragma unroll
        for (int off = 32; off > 0; off >>= 1) {
            p1 += __shfl_xor(p1, off, 64);
            p2 += __shfl_xor(p2, off, 64);
        }
        if (lane == 0) { s1[n] = p1; s2[n] = p2; }

        float ua = 0.f;
        #pragma unroll 8
        for (int k = 0; k < D; ++k)
            ua = fmaf(lz[wid][k], lWt1[k * D + lane], ua);
        u[(size_t)n * D + lane] = ua;
    }
}

// ---------------------------------------------------------------------------
// CSR build: histogram -> exclusive scan (3 kernels) -> scatter permutation
// ---------------------------------------------------------------------------
__global__ __launch_bounds__(256) void hist_kernel(
    const int* __restrict__ dst, int* __restrict__ count)
{
    int i = blockIdx.x * 256 + threadIdx.x;
    const int stride = gridDim.x * 256;
    for (; i < N_EDGES; i += stride) atomicAdd(&count[dst[i]], 1);
}

__global__ __launch_bounds__(256) void scan_sum_kernel(
    const int* __restrict__ count, int* __restrict__ bsum)
{
    __shared__ int s[256];
    const int t = threadIdx.x;
    const int idx = blockIdx.x * 256 + t;
    s[t] = (idx < N_NODES) ? count[idx] : 0;
    __syncthreads();
    for (int off = 128; off > 0; off >>= 1) {
        if (t < off) s[t] += s[t + off];
        __syncthreads();
    }
    if (t == 0) bsum[blockIdx.x] = s[0];
}

__global__ __launch_bounds__(256) void scan_top_kernel(int* __restrict__ bsum)
{
    __shared__ int s[256];
    const int t = threadIdx.x;
    const int v = (t < N_CHUNKS) ? bsum[t] : 0;
    s[t] = v;
    __syncthreads();
    for (int off = 1; off < 256; off <<= 1) {
        int x = (t >= off) ? s[t - off] : 0;
        __syncthreads();
        s[t] += x;
        __syncthreads();
    }
    if (t < N_CHUNKS) bsum[t] = s[t] - v;   // exclusive of chunk sums
}

__global__ __launch_bounds__(256) void scan_local_kernel(
    const int* __restrict__ count, const int* __restrict__ bsum,
    int* __restrict__ offsets, int* __restrict__ cursor)
{
    __shared__ int s[256];
    const int t = threadIdx.x;
    const int idx = blockIdx.x * 256 + t;
    const int v = (idx < N_NODES) ? count[idx] : 0;
    s[t] = v;
    __syncthreads();
    for (int off = 1; off < 256; off <<= 1) {
        int x = (t >= off) ? s[t - off] : 0;
        __syncthreads();
        s[t] += x;
        __syncthreads();
    }
    if (idx < N_NODES) {
        int e = bsum[blockIdx.x] + s[t] - v;  // exclusive prefix
        offsets[idx] = e;
        cursor[idx]  = e;
    }
}

__global__ __launch_bounds__(256) void scatter_kernel(
    const int* __restrict__ src, const int* __restrict__ dst,
    int* __restrict__ cursor, int* __restrict__ pe, int* __restrict__ ps)
{
    int i = blockIdx.x * 256 + threadIdx.x;
    const int stride = gridDim.x * 256;
    for (; i < N_EDGES; i += stride) {
        const int d = dst[i];
        const int pos = atomicAdd(&cursor[d], 1);
        pe[pos] = i;
        ps[pos] = src[i];
    }
}

// ---------------------------------------------------------------------------
// K2: sorted edge pass A + fused node finalize.
// One wave per dst node: walk its incoming-edge segment, accumulate
// Σ ex·t and Σ ex in registers, then h_new + p/q in one go. No atomics.
// ---------------------------------------------------------------------------
__global__ __launch_bounds__(256) void edge_a_sorted_kernel(
    const float* __restrict__ edge_w,
    const int* __restrict__ pe, const int* __restrict__ ps,
    const int* __restrict__ offsets, const int* __restrict__ count,
    const float* __restrict__ Wa, const float* __restrict__ Wt,
    const float* __restrict__ We,
    const float* __restrict__ u, const float* __restrict__ s1,
    const float* __restrict__ s2, const float* __restrict__ z,
    float* __restrict__ hout, float* __restrict__ p, float* __restrict__ q)
{
    __shared__ float lWE[D * 64];   // [j][l]: l<32 -> We1[j][l], else We2[j][l-32]
    __shared__ float lh[4][D];
    const int tid = threadIdx.x;
    for (int i = tid; i < D * 64; i += 256) {
        int j = i >> 6, l = i & 63;
        lWE[i] = We[(j + ((l < 32) ? 0 : D)) * E_OUT + (l & 31)];
    }
    __syncthreads();

    const int wid = tid >> 6, lane = tid & 63;
    const int nwaves = gridDim.x * 4;

    float wt2r[E_IN], war[E_IN];
    #pragma unroll
    for (int k = 0; k < E_IN; ++k) {
        wt2r[k] = Wt[(D + k) * D + lane];   // lane j holds W_tonode[64+k][j]
        war[k]  = Wa[2 * D + k];            // lane-invariant
    }

    for (int n = blockIdx.x * 4 + wid; n < N_NODES; n += nwaves) {
        const int off = offsets[n];
        const int deg = count[n];
        const float s2n = s2[n];
        float acc = 0.f, den = 0.f;

        for (int b = 0; b < deg; b += 64) {
            int rem = deg - b; if (rem > 64) rem = 64;
            int eb = 0, sb = 0;
            if (lane < rem) {
                eb = pe[off + b + lane];
                sb = ps[off + b + lane];
            }
            for (int i = 0; i < rem; ++i) {
                const int e = __builtin_amdgcn_readlane(eb, i);
                const int s = __builtin_amdgcn_readlane(sb, i);
                const float* __restrict__ ewr = edge_w + (size_t)e * E_IN;
                float a = s1[s] + s2n;
                float t = u[(size_t)s * D + lane];
                #pragma unroll
                for (int k = 0; k < E_IN; ++k) {
                    const float w = ewr[k];        // wave-uniform -> s_load
                    a = fmaf(w, war[k], a);
                    t = fmaf(w, wt2r[k], t);
                }
                const float lr = (a > 0.f) ? a : 0.1f * a;
                const float ex = __expf(lr);
                acc = fmaf(ex, t, acc);
                den += ex;
            }
        }

        const float hv = (deg > 0) ? acc / den : z[(size_t)n * D + lane];
        hout[(size_t)n * D + lane] = hv;
        lh[wid][lane] = hv;

        float pacc = 0.f;
        #pragma unroll 8
        for (int j = 0; j < D; ++j)
            pacc = fmaf(lh[wid][j], lWE[j * 64 + lane], pacc);

        float* o = (lane < 32) ? p : q;
        o[(size_t)n * E_OUT + (lane & 31)] = pacc;
    }
}

// ---------------------------------------------------------------------------
// K3: edge pass B. Two edges per wave, lane&31 owns an output column.
//   w = p[src] + q[dst] + ew @ W_edge[128:]
// ---------------------------------------------------------------------------
__global__ __launch_bounds__(256) void edge_b_kernel(
    const float* __restrict__ edge_w, const int* __restrict__ src,
    const int* __restrict__ dst, const float* __restrict__ We,
    const float* __restrict__ p, const float* __restrict__ q,
    float* __restrict__ wout)
{
    const int lane = threadIdx.x & 63;
    const int i = lane & 31;
    const int half = lane >> 5;
    const int wp0 = blockIdx.x * 4 + (threadIdx.x >> 6);
    const int npairs = N_EDGES / 2;
    const int nw = gridDim.x * 4;

    float we3r[E_IN];
    #pragma unroll
    for (int k = 0; k < E_IN; ++k) we3r[k] = We[(2 * D + k) * E_OUT + i];

    for (int wp = wp0; wp < npairs; wp += nw) {
        const int e = 2 * wp + half;
        const int s = src[e], d = dst[e];
        float acc = p[(size_t)s * E_OUT + i] + q[(size_t)d * E_OUT + i];
        const float4* ew4 = (const float4*)(edge_w + (size_t)e * E_IN);
        #pragma unroll
        for (int qq = 0; qq < E_IN / 4; ++qq) {
            float4 v = ew4[qq];
            acc = fmaf(v.x, we3r[4*qq+0], acc);
            acc = fmaf(v.y, we3r[4*qq+1], acc);
            acc = fmaf(v.z, we3r[4*qq+2], acc);
            acc = fmaf(v.w, we3r[4*qq+3], acc);
        }
        wout[(size_t)e * E_OUT + i] = acc;
    }
}

// ---------------------------------------------------------------------------
extern "C" void kernel_launch(void* const* d_in, const int* in_sizes, int n_in,
                              void* d_out, int out_size, void* d_ws, size_t ws_size,
                              hipStream_t stream) {
    const float* h  = (const float*)d_in[0];
    const float* ew = (const float*)d_in[1];
    const float* Wn = (const float*)d_in[2];
    const float* Wa = (const float*)d_in[3];
    const float* Wt = (const float*)d_in[4];
    const float* We = (const float*)d_in[5];
    const int* src  = (const int*)d_in[6];
    const int* dst  = (const int*)d_in[7];

    float* z    = (float*)d_ws;                       // N*64
    float* u    = z + (size_t)N_NODES * D;            // N*64
    float* s1   = u + (size_t)N_NODES * D;            // N
    float* s2   = s1 + N_NODES;                       // N
    float* p    = s2 + N_NODES;                       // N*32
    float* q    = p + (size_t)N_NODES * E_OUT;        // N*32
    int* counts = (int*)(q + (size_t)N_NODES * E_OUT);// N
    int* offs   = counts + N_NODES;                   // N
    int* cursor = offs + N_NODES;                     // N
    int* bsum   = cursor + N_NODES;                   // 256
    int* pe     = bsum + 256;                         // E
    int* ps     = pe + N_EDGES;                       // E

    float* hout = (float*)d_out;
    float* wout = hout + (size_t)N_NODES * D;

    hipMemsetAsync(counts, 0, N_NODES * sizeof(int), stream);

    node_a_kernel<<<1024, 256, 0, stream>>>(h, Wn, Wa, Wt, z, u, s1, s2);
    hist_kernel<<<1024, 256, 0, stream>>>(dst, counts);
    scan_sum_kernel<<<N_CHUNKS, 256, 0, stream>>>(counts, bsum);
    scan_top_kernel<<<1, 256, 0, stream>>>(bsum);
    scan_local_kernel<<<N_CHUNKS, 256, 0, stream>>>(counts, bsum, offs, cursor);
    scatter_kernel<<<1024, 256, 0, stream>>>(src, dst, cursor, pe, ps);
    edge_a_sorted_kernel<<<2048, 256, 0, stream>>>(ew, pe, ps, offs, counts,
                                                   Wa, Wt, We, u, s1, s2, z,
                                                   hout, p, q);
    edge_b_kernel<<<2048, 256, 0, stream>>>(ew, src, dst, We, p, q, wout);
}